// Round 8
// baseline (23.876 us; speedup 1.0000x reference)
//
#include <hip/hip_runtime.h>

// YOLOv2 loss. preds [B,S,S,A,25] f32, labels [B,S,S,25] f32, out scalar f32.
// v8 = v7 body (vectorized thread-per-cell, early-out) + fused reduction via
// ONE relaxed atomicAdd per block (no fences, no counter, no 2nd kernel).
constexpr int kB     = 1024;
constexpr int kS     = 13;
constexpr int kA     = 5;
constexpr int kC5    = 25;
constexpr int kRec   = kA * kC5;          // 125
constexpr int kCells = kB * kS * kS;      // 173056
constexpr int kBlock = 256;
constexpr int kNBlk  = (kCells + kBlock - 1) / kBlock;  // 676 (exact)

using f4 = __attribute__((__ext_vector_type__(4))) float;

__device__ __forceinline__ f4 ld4(const float* __restrict__ p) {
    f4 r;
    __builtin_memcpy(&r, p, sizeof(r));   // dword-aligned dwordx4 on gfx950
    return r;
}

__global__ __launch_bounds__(kBlock)
void yolo_main(const float* __restrict__ preds,
               const float* __restrict__ labels,
               float* __restrict__ out)
{
    const int tid  = threadIdx.x;
    const int lane = tid & 63;
    const int wid  = tid >> 6;
    const int cell = blockIdx.x * kBlock + tid;

    float loss = 0.0f;
    if (cell < kCells) {
        const float* __restrict__ lab = labels + (size_t)cell * kC5;
        const f4 g = ld4(lab + 1);                 // {ly, lw, lh, obj}
        if (g.w == 1.0f) {
            const float lx = lab[0], ly = g.x, lw = g.y, lh = g.z;
            const float lx1 = lx - lw * 0.5f, lx2 = lx + lw * 0.5f;
            const float ly1 = ly - lh * 0.5f, ly2 = ly + lh * 0.5f;
            const float larea = lw * lh;

            const float* __restrict__ p = preds + (size_t)cell * kRec;
            f4   box[kA];
            float iou[kA], conf[kA];
            int best = 0;
            float bestIou = -1.0f;
            #pragma unroll
            for (int a = 0; a < kA; ++a) {
                const float* pa = p + a * kC5;
                const f4 b = ld4(pa);              // {x, y, w, h}
                box[a]  = b;
                conf[a] = pa[4];
                const float px1 = b.x - b.z * 0.5f, px2 = b.x + b.z * 0.5f;
                const float py1 = b.y - b.w * 0.5f, py2 = b.y + b.w * 0.5f;
                const float iw = fmaxf(fminf(px2, lx2) - fmaxf(px1, lx1), 0.0f);
                const float ih = fmaxf(fminf(py2, ly2) - fmaxf(py1, ly1), 0.0f);
                const float inter = iw * ih;
                const float uni = b.z * b.w + larea - inter;
                const float v = inter / (uni + 1e-12f);
                iou[a] = v;
                if (v > bestIou) { bestIou = v; best = a; }  // strict > == jnp.argmax
            }

            const f4 bb = box[best];
            const float dx = lx - bb.x, dy = ly - bb.y;
            loss += 5.0f * (dx * dx + dy * dy);
            const float sw = sqrtf(lw) - sqrtf(bb.z);
            const float sh = sqrtf(lh) - sqrtf(bb.w);
            loss += sw * sw + sh * sh;
            const float dob = bestIou - conf[best];
            loss += dob * dob;
            // cls: record's lines already in L1 from box/conf loads
            const float* __restrict__ bp = p + best * kC5;
            float cls = 0.0f;
            #pragma unroll
            for (int r = 0; r < 5; ++r) {
                const f4 lv = ld4(lab + 5 + 4 * r);
                const f4 pv = ld4(bp + 5 + 4 * r);
                const f4 d  = lv - pv;
                cls += d.x * d.x + d.y * d.y + d.z * d.z + d.w * d.w;
            }
            loss += cls;
            #pragma unroll
            for (int a = 0; a < kA; ++a) {
                if (a != best && iou[a] < 0.6f) {
                    const float d = iou[a] - conf[a];
                    loss += d * d;
                }
            }
        }
    }

    // block reduction: wave shuffle -> LDS -> one plain atomicAdd per block
    #pragma unroll
    for (int off = 32; off > 0; off >>= 1)
        loss += __shfl_down(loss, off, 64);
    __shared__ float sred[kBlock / 64];
    if (lane == 0) sred[wid] = loss;
    __syncthreads();
    if (tid == 0) {
        const float s = sred[0] + sred[1] + sred[2] + sred[3];
        atomicAdd(out, s * (1.0f / (float)kB));   // relaxed, device-scope default
    }
}

extern "C" void kernel_launch(void* const* d_in, const int* in_sizes, int n_in,
                              void* d_out, int out_size, void* d_ws, size_t ws_size,
                              hipStream_t stream) {
    const float* preds  = (const float*)d_in[0];
    const float* labels = (const float*)d_in[1];
    float* out = (float*)d_out;

    // out must be zero at kernel start every call (poisoned once, then stale
    // after each replay): async memset is graph-capture legal.
    hipMemsetAsync(out, 0, sizeof(float), stream);
    yolo_main<<<kNBlk, kBlock, 0, stream>>>(preds, labels, out);
}

// Round 9
// 22.215 us; speedup vs baseline: 1.0748x; 1.0748x over previous
//
#include <hip/hip_runtime.h>

// YOLOv2 loss. preds [B,S,S,A,25] f32, labels [B,S,S,25] f32, out scalar f32.
// v9: coalesced, register-batched gather of object records into LDS
// (32-deep predicated unroll -> all loads in flight, one latency), compute
// from LDS, no atomics, two kernels.
constexpr int kB     = 1024;
constexpr int kS     = 13;
constexpr int kA     = 5;
constexpr int kC5    = 25;
constexpr int kRec   = kA * kC5;           // 125 floats / record
constexpr int kCells = kB * kS * kS;       // 173056
constexpr int kBlock = 256;
constexpr int kCPB   = 64;                 // cells per block
constexpr int kNBlk  = kCells / kCPB;      // 2704 exact
constexpr int kSS    = 129;                // LDS record slot stride (floats)
static_assert(kCells % kCPB == 0, "exact tiling");

__global__ __launch_bounds__(kBlock)
void yolo_main(const float* __restrict__ preds,
               const float* __restrict__ labels,
               float* __restrict__ partial)
{
    __shared__ __align__(16) float lab[kCPB * kC5];   // 6400 B
    __shared__ float prec[kCPB * kSS];                // 33 KB
    __shared__ unsigned short objIdx[kCPB];
    __shared__ int nObjS;

    const int tid  = threadIdx.x;
    const int lane = tid & 63;
    const int wid  = tid >> 6;
    const size_t cellBase = (size_t)blockIdx.x * kCPB;

    // ---- 1) stage labels, coalesced float4 (6400 B / block) ----
    {
        const float4* __restrict__ src = (const float4*)(labels + cellBase * kC5);
        float4* dst = (float4*)lab;
        dst[tid] = src[tid];
        if (tid < (kCPB * kC5 / 4) - kBlock)          // 400-256 = 144
            dst[kBlock + tid] = src[kBlock + tid];
    }
    __syncthreads();

    // ---- 2) wave 0: ballot-compact object cells ----
    if (wid == 0) {
        const bool isObj = (lab[lane * kC5 + 4] == 1.0f);
        const unsigned long long bm = __ballot(isObj);
        if (isObj) objIdx[__popcll(bm & ((1ull << lane) - 1ull))] = (unsigned short)lane;
        if (lane == 0) nObjS = __popcll(bm);
    }
    __syncthreads();
    const int nObj  = nObjS;
    const int total = nObj << 7;          // nObj * 128 (padded record slots)

    // ---- 3) coalesced register-batched gather ----
    // idx = k*256 + tid; rec = idx>>7; dw = idx&127. Each wave's 64 lanes read
    // 64 CONSECUTIVE dwords of one record (2 lines/instr, no amplification).
    // All loads independent -> issued together -> one memory latency.
    const float* __restrict__ pb = preds + cellBase * kRec;
    float v[32];
    #pragma unroll
    for (int k = 0; k < 32; ++k) {
        if ((k << 8) >= total) break;                 // block-uniform early exit
        const int idx = (k << 8) + tid;
        const int rec = idx >> 7;
        const int dw  = idx & 127;
        const bool val = (idx < total) && (dw < kRec);
        v[k] = val ? pb[(int)objIdx[rec] * kRec + dw] : 0.0f;
    }
    #pragma unroll
    for (int k = 0; k < 32; ++k) {
        if ((k << 8) >= total) break;
        const int idx = (k << 8) + tid;
        const int rec = idx >> 7;
        const int dw  = idx & 127;
        if ((idx < total) && (dw < kRec))
            prec[rec * kSS + dw] = v[k];              // bank (tid+c)%32: free
    }
    __syncthreads();

    // ---- 4) compute: slot-per-thread, all operands in LDS ----
    float loss = 0.0f;
    if (tid < nObj) {
        const int lc = objIdx[tid];
        const float* __restrict__ L = lab + lc * kC5;
        const float* __restrict__ P = prec + tid * kSS;   // [a*25 + j]

        const float lx = L[0], ly = L[1], lw = L[2], lh = L[3];
        const float lx1 = lx - lw * 0.5f, lx2 = lx + lw * 0.5f;
        const float ly1 = ly - lh * 0.5f, ly2 = ly + lh * 0.5f;
        const float larea = lw * lh;

        float iou[kA], conf[kA];
        int best = 0;
        float bestIou = -1.0f;
        #pragma unroll
        for (int a = 0; a < kA; ++a) {
            const float px = P[a * kC5 + 0], py = P[a * kC5 + 1];
            const float pw = P[a * kC5 + 2], ph = P[a * kC5 + 3];
            conf[a] = P[a * kC5 + 4];
            const float px1 = px - pw * 0.5f, px2 = px + pw * 0.5f;
            const float py1 = py - ph * 0.5f, py2 = py + ph * 0.5f;
            const float iw = fmaxf(fminf(px2, lx2) - fmaxf(px1, lx1), 0.0f);
            const float ih = fmaxf(fminf(py2, ly2) - fmaxf(py1, ly1), 0.0f);
            const float inter = iw * ih;
            const float uni = pw * ph + larea - inter;
            const float t = inter / (uni + 1e-12f);
            iou[a] = t;
            if (t > bestIou) { bestIou = t; best = a; }   // strict > == jnp.argmax
        }

        const float dx = lx - P[best * kC5 + 0], dy = ly - P[best * kC5 + 1];
        loss += 5.0f * (dx * dx + dy * dy);
        const float sw = sqrtf(lw) - sqrtf(P[best * kC5 + 2]);
        const float sh = sqrtf(lh) - sqrtf(P[best * kC5 + 3]);
        loss += sw * sw + sh * sh;
        const float dob = bestIou - conf[best];
        loss += dob * dob;
        float cls = 0.0f;
        #pragma unroll
        for (int j = 5; j < kC5; ++j) {
            const float d = L[j] - P[best * kC5 + j];
            cls += d * d;
        }
        loss += cls;
        #pragma unroll
        for (int a = 0; a < kA; ++a) {
            if (a != best && iou[a] < 0.6f) {
                const float d = iou[a] - conf[a];
                loss += d * d;
            }
        }
    }

    // ---- 5) reduce: loss nonzero only in wave 0 ----
    if (wid == 0) {
        #pragma unroll
        for (int off = 32; off > 0; off >>= 1)
            loss += __shfl_down(loss, off, 64);
        if (lane == 0) partial[blockIdx.x] = loss;
    }
}

__global__ __launch_bounds__(1024)
void yolo_reduce(const float* __restrict__ partial, float* __restrict__ out)
{
    float s = 0.0f;
    for (int i = threadIdx.x; i < kNBlk; i += 1024)
        s += partial[i];
    #pragma unroll
    for (int off = 32; off > 0; off >>= 1)
        s += __shfl_down(s, off, 64);
    __shared__ float sred[16];
    const int lane = threadIdx.x & 63;
    const int wid  = threadIdx.x >> 6;
    if (lane == 0) sred[wid] = s;
    __syncthreads();
    if (threadIdx.x == 0) {
        float t = 0.0f;
        #pragma unroll
        for (int w = 0; w < 16; ++w) t += sred[w];
        out[0] = t * (1.0f / (float)kB);
    }
}

extern "C" void kernel_launch(void* const* d_in, const int* in_sizes, int n_in,
                              void* d_out, int out_size, void* d_ws, size_t ws_size,
                              hipStream_t stream) {
    const float* preds  = (const float*)d_in[0];
    const float* labels = (const float*)d_in[1];
    float* out     = (float*)d_out;
    float* partial = (float*)d_ws;          // 2704 floats, fully rewritten each call

    yolo_main<<<kNBlk, kBlock, 0, stream>>>(preds, labels, partial);
    yolo_reduce<<<1, 1024, 0, stream>>>(partial, out);
}

// Round 10
// 15.918 us; speedup vs baseline: 1.5000x; 1.3956x over previous
//
#include <hip/hip_runtime.h>

// YOLOv2 loss. preds [B,S,S,A,25] f32, labels [B,S,S,25] f32, out scalar f32.
// v10 == v7 (best measured: 15.97 us). Thread-per-cell, early-out on
// objectness, dwordx4-vectorized loads, two kernels, no atomics/fences.
//
// Why this shape (measured across 9 rounds):
//  - gated scatter reads ~24 MB HBM/replay at scattered-line efficiency
//    (~2.4 TB/s) -> K1 ~10 us = scatter roofline; staging/coalescing
//    variants all slower (18.5-22.2 us).
//  - reduction via 2nd kernel is cheapest: atomicAdd +8 us, fences +30 us
//    (cross-XCD L2 writeback).
constexpr int kB     = 1024;
constexpr int kS     = 13;
constexpr int kA     = 5;
constexpr int kC5    = 25;
constexpr int kRec   = kA * kC5;          // 125
constexpr int kCells = kB * kS * kS;      // 173056
constexpr int kBlock = 256;
constexpr int kNBlk  = (kCells + kBlock - 1) / kBlock;  // 676 (exact)

using f4 = __attribute__((__ext_vector_type__(4))) float;

__device__ __forceinline__ f4 ld4(const float* __restrict__ p) {
    f4 r;
    __builtin_memcpy(&r, p, sizeof(r));   // dword-aligned dwordx4 on gfx950
    return r;
}

__global__ __launch_bounds__(kBlock)
void yolo_main(const float* __restrict__ preds,
               const float* __restrict__ labels,
               float* __restrict__ partial)
{
    const int tid  = threadIdx.x;
    const int lane = tid & 63;
    const int wid  = tid >> 6;
    const int cell = blockIdx.x * kBlock + tid;

    float loss = 0.0f;
    if (cell < kCells) {
        const float* __restrict__ lab = labels + (size_t)cell * kC5;
        const f4 g = ld4(lab + 1);                 // {ly, lw, lh, obj}
        if (g.w == 1.0f) {
            const float lx = lab[0], ly = g.x, lw = g.y, lh = g.z;
            const float lx1 = lx - lw * 0.5f, lx2 = lx + lw * 0.5f;
            const float ly1 = ly - lh * 0.5f, ly2 = ly + lh * 0.5f;
            const float larea = lw * lh;

            const float* __restrict__ p = preds + (size_t)cell * kRec;
            f4   box[kA];
            float iou[kA], conf[kA];
            int best = 0;
            float bestIou = -1.0f;
            #pragma unroll
            for (int a = 0; a < kA; ++a) {
                const float* pa = p + a * kC5;
                const f4 b = ld4(pa);              // {x, y, w, h} one dwordx4
                box[a]  = b;
                conf[a] = pa[4];
                const float px1 = b.x - b.z * 0.5f, px2 = b.x + b.z * 0.5f;
                const float py1 = b.y - b.w * 0.5f, py2 = b.y + b.w * 0.5f;
                const float iw = fmaxf(fminf(px2, lx2) - fmaxf(px1, lx1), 0.0f);
                const float ih = fmaxf(fminf(py2, ly2) - fmaxf(py1, ly1), 0.0f);
                const float inter = iw * ih;
                const float uni = b.z * b.w + larea - inter;
                const float v = inter / (uni + 1e-12f);
                iou[a] = v;
                if (v > bestIou) { bestIou = v; best = a; }  // strict > == jnp.argmax
            }

            const f4 bb = box[best];
            // xy
            const float dx = lx - bb.x, dy = ly - bb.y;
            loss += 5.0f * (dx * dx + dy * dy);
            // wh
            const float sw = sqrtf(lw) - sqrtf(bb.z);
            const float sh = sqrtf(lh) - sqrtf(bb.w);
            loss += sw * sw + sh * sh;
            // obj
            const float dob = bestIou - conf[best];
            loss += dob * dob;
            // cls: 20 floats each side = 5 dwordx4 each (4-B aligned)
            const float* __restrict__ bp = p + best * kC5;
            float cls = 0.0f;
            #pragma unroll
            for (int r = 0; r < 5; ++r) {
                const f4 lv = ld4(lab + 5 + 4 * r);
                const f4 pv = ld4(bp + 5 + 4 * r);
                const f4 d  = lv - pv;
                cls += d.x * d.x + d.y * d.y + d.z * d.z + d.w * d.w;
            }
            loss += cls;
            // noobj
            #pragma unroll
            for (int a = 0; a < kA; ++a) {
                if (a != best && iou[a] < 0.6f) {
                    const float d = iou[a] - conf[a];
                    loss += d * d;
                }
            }
        }
    }

    // block reduction: wave shuffle then LDS (no atomics, no fences)
    #pragma unroll
    for (int off = 32; off > 0; off >>= 1)
        loss += __shfl_down(loss, off, 64);
    __shared__ float sred[kBlock / 64];
    if (lane == 0) sred[wid] = loss;
    __syncthreads();
    if (tid == 0)
        partial[blockIdx.x] = sred[0] + sred[1] + sred[2] + sred[3];
}

__global__ __launch_bounds__(kBlock)
void yolo_reduce(const float* __restrict__ partial, float* __restrict__ out)
{
    float s = 0.0f;
    for (int i = threadIdx.x; i < kNBlk; i += kBlock)
        s += partial[i];
    #pragma unroll
    for (int off = 32; off > 0; off >>= 1)
        s += __shfl_down(s, off, 64);
    __shared__ float sred[kBlock / 64];
    const int lane = threadIdx.x & 63;
    const int wid  = threadIdx.x >> 6;
    if (lane == 0) sred[wid] = s;
    __syncthreads();
    if (threadIdx.x == 0) {
        float t = 0.0f;
        #pragma unroll
        for (int w = 0; w < kBlock / 64; ++w) t += sred[w];
        out[0] = t * (1.0f / (float)kB);
    }
}

extern "C" void kernel_launch(void* const* d_in, const int* in_sizes, int n_in,
                              void* d_out, int out_size, void* d_ws, size_t ws_size,
                              hipStream_t stream) {
    const float* preds  = (const float*)d_in[0];
    const float* labels = (const float*)d_in[1];
    float* out     = (float*)d_out;
    float* partial = (float*)d_ws;          // 676 floats; fully rewritten by K1 each call

    yolo_main<<<kNBlk, kBlock, 0, stream>>>(preds, labels, partial);
    yolo_reduce<<<1, kBlock, 0, stream>>>(partial, out);
}